// Round 2
// baseline (1255.119 us; speedup 1.0000x reference)
//
#include <hip/hip_runtime.h>

#define NCLS 19
#define NROW 20          // 19 classes + 1 dump row for out-of-range labels
#define NLANE 64
#define NCH 256
#define NPIX 65536       // 256*256
#define NBATCH 4
#define TPB 256
#define EPSV 1e-5f
#define CNT_THRESH 6

// One block per (batch, channel). Accumulate per-class {sum, sumsq, count}
// via fire-and-forget ds_add_f32 into per-lane LDS columns (no RMW chain,
// no branches). acc addr bank = lane%32 -> only the free 2-way aliasing.
__global__ __launch_bounds__(TPB) void moment_kernel(const float* __restrict__ x,
                                                     const int* __restrict__ y,
                                                     float* __restrict__ out) {
    __shared__ float acc[3][NROW][NLANE];   // {sum, sumsq, count}[class][lane] = 15 KB
    const int tid  = threadIdx.x;
    const int lane = tid & 63;
    const int c = blockIdx.x;
    const int b = blockIdx.y;

    for (int i = tid; i < 3 * NROW * NLANE; i += TPB) ((float*)acc)[i] = 0.f;
    __syncthreads();

    const float4* xp = (const float4*)(x + ((size_t)(b * NCH + c)) * NPIX);
    const int4*   yp = (const int4*)(y + (size_t)b * NPIX);

    #pragma unroll 4
    for (int it = 0; it < NPIX / (TPB * 4); ++it) {   // 64 iterations
        const int idx = it * TPB + tid;
        float4 v = xp[idx];
        int4   l = yp[idx];
        int k0 = min((unsigned)l.x, (unsigned)NCLS);  // invalid -> dump row 19
        int k1 = min((unsigned)l.y, (unsigned)NCLS);
        int k2 = min((unsigned)l.z, (unsigned)NCLS);
        int k3 = min((unsigned)l.w, (unsigned)NCLS);
        unsafeAtomicAdd(&acc[0][k0][lane], v.x);
        unsafeAtomicAdd(&acc[1][k0][lane], v.x * v.x);
        unsafeAtomicAdd(&acc[2][k0][lane], 1.0f);
        unsafeAtomicAdd(&acc[0][k1][lane], v.y);
        unsafeAtomicAdd(&acc[1][k1][lane], v.y * v.y);
        unsafeAtomicAdd(&acc[2][k1][lane], 1.0f);
        unsafeAtomicAdd(&acc[0][k2][lane], v.z);
        unsafeAtomicAdd(&acc[1][k2][lane], v.z * v.z);
        unsafeAtomicAdd(&acc[2][k2][lane], 1.0f);
        unsafeAtomicAdd(&acc[0][k3][lane], v.w);
        unsafeAtomicAdd(&acc[1][k3][lane], v.w * v.w);
        unsafeAtomicAdd(&acc[2][k3][lane], 1.0f);
    }
    __syncthreads();

    // Wave w reduces classes w, w+4, ... via 64-lane butterfly.
    const int w = tid >> 6;
    for (int k = w; k < NCLS; k += 4) {
        float s = acc[0][k][lane];
        float q = acc[1][k][lane];
        float n = acc[2][k][lane];
        for (int off = 32; off > 0; off >>= 1) {
            s += __shfl_down(s, off);
            q += __shfl_down(q, off);
            n += __shfl_down(n, off);
        }
        if (lane == 0) {
            const bool valid = n > (float)CNT_THRESH;
            float mean = s / fmaxf(n, 1.0f);
            float var  = fmaxf((q - n * mean * mean) / fmaxf(n - 1.0f, 1.0f), 0.0f);
            float m_out = valid ? mean : 0.0f;
            float s_out = valid ? (sqrtf(var) + EPSV) : 0.0f;
            const int o = (b * NCLS + k) * NCH + c;
            out[o] = m_out;                                          // means [4,19,256]
            out[NBATCH * NCLS * NCH + o] = s_out;                    // stds  [4,19,256]
            if (c == 0)
                out[2 * NBATCH * NCLS * NCH + b * NCLS + k] = valid ? 1.0f : 0.0f;  // valid [4,19]
        }
    }
}

extern "C" void kernel_launch(void* const* d_in, const int* in_sizes, int n_in,
                              void* d_out, int out_size, void* d_ws, size_t ws_size,
                              hipStream_t stream) {
    const float* x = (const float*)d_in[0];
    const int*   y = (const int*)d_in[1];
    float* out = (float*)d_out;

    dim3 grid(NCH, NBATCH);
    moment_kernel<<<grid, TPB, 0, stream>>>(x, y, out);
}

// Round 3
// 427.104 us; speedup vs baseline: 2.9387x; 2.9387x over previous
//
#include <hip/hip_runtime.h>

#define NCLS 19
#define NCH 256
#define NPIX 65536       // 256*256
#define NBATCH 4
#define TPB 256
#define EPSV 1e-5f
#define CNT_THRESH 6

// One block per (batch, channel). Dense 19-class predicated accumulation in
// VGPRs (no LDS, no atomics, no branches in the hot loop). Counts via scalar
// ballot+popcount (wave-uniform, rides the scalar pipe for free).
__global__ __launch_bounds__(TPB) void moment_kernel(const float* __restrict__ x,
                                                     const int* __restrict__ y,
                                                     float* __restrict__ out) {
    const int tid  = threadIdx.x;
    const int lane = tid & 63;
    const int w    = tid >> 6;
    const int c = blockIdx.x;
    const int b = blockIdx.y;

    float s[NCLS], q[NCLS];
    int cnt[NCLS];   // wave-uniform (ballot/popcount) -> lives in SGPRs
    #pragma unroll
    for (int k = 0; k < NCLS; ++k) { s[k] = 0.f; q[k] = 0.f; cnt[k] = 0; }

    const float4* xp = (const float4*)(x + ((size_t)(b * NCH + c)) * NPIX);
    const int4*   yp = (const int4*)(y + (size_t)b * NPIX);

    for (int it = tid; it < NPIX / 4; it += TPB) {   // 64 iterations
        float4 v = xp[it];
        int4   l = yp[it];
        #pragma unroll
        for (int k = 0; k < NCLS; ++k) {
            bool m0 = (l.x == k); float t0 = m0 ? v.x : 0.f;
            bool m1 = (l.y == k); float t1 = m1 ? v.y : 0.f;
            bool m2 = (l.z == k); float t2 = m2 ? v.z : 0.f;
            bool m3 = (l.w == k); float t3 = m3 ? v.w : 0.f;
            s[k] += t0; q[k] = fmaf(t0, t0, q[k]);
            s[k] += t1; q[k] = fmaf(t1, t1, q[k]);
            s[k] += t2; q[k] = fmaf(t2, t2, q[k]);
            s[k] += t3; q[k] = fmaf(t3, t3, q[k]);
            cnt[k] += (int)__popcll(__ballot(m0)) + (int)__popcll(__ballot(m1))
                    + (int)__popcll(__ballot(m2)) + (int)__popcll(__ballot(m3));
        }
    }

    // Reduce: 64-lane butterfly per class, then 4 wave-partials via LDS.
    __shared__ float red_s[4][NCLS];
    __shared__ float red_q[4][NCLS];
    __shared__ int   red_n[4][NCLS];
    #pragma unroll
    for (int k = 0; k < NCLS; ++k) {
        float sv = s[k], qv = q[k];
        for (int off = 32; off > 0; off >>= 1) {
            sv += __shfl_down(sv, off);
            qv += __shfl_down(qv, off);
        }
        if (lane == 0) { red_s[w][k] = sv; red_q[w][k] = qv; red_n[w][k] = cnt[k]; }
    }
    __syncthreads();

    if (tid < NCLS) {
        const int k = tid;
        float sv = 0.f, qv = 0.f; int n = 0;
        #pragma unroll
        for (int i = 0; i < 4; ++i) { sv += red_s[i][k]; qv += red_q[i][k]; n += red_n[i][k]; }
        const float nf = (float)n;
        const bool valid = n > CNT_THRESH;
        float mean = sv / fmaxf(nf, 1.0f);
        float var  = fmaxf((qv - nf * mean * mean) / fmaxf(nf - 1.0f, 1.0f), 0.0f);
        const int o = (b * NCLS + k) * NCH + c;
        out[o] = valid ? mean : 0.0f;                                  // means [4,19,256]
        out[NBATCH * NCLS * NCH + o] = valid ? (sqrtf(var) + EPSV) : 0.0f;  // stds [4,19,256]
        if (c == 0)
            out[2 * NBATCH * NCLS * NCH + b * NCLS + k] = valid ? 1.0f : 0.0f;  // valid [4,19]
    }
}

extern "C" void kernel_launch(void* const* d_in, const int* in_sizes, int n_in,
                              void* d_out, int out_size, void* d_ws, size_t ws_size,
                              hipStream_t stream) {
    const float* x = (const float*)d_in[0];
    const int*   y = (const int*)d_in[1];
    float* out = (float*)d_out;

    dim3 grid(NCH, NBATCH);
    moment_kernel<<<grid, TPB, 0, stream>>>(x, y, out);
}

// Round 4
// 402.928 us; speedup vs baseline: 3.1150x; 1.0600x over previous
//
#include <hip/hip_runtime.h>

#define NCLS 19
#define NCH 256
#define NPIX 65536       // 256*256
#define NBATCH 4
#define TPB 256
#define EPSV 1e-5f
#define CNT_THRESH 6
#define CSEG 16                    // count-kernel segments per batch
#define SEGPIX (NPIX / CSEG)       // 4096 labels per count block

typedef float v2f __attribute__((ext_vector_type(2)));

// ---- kernel 1: parallel label histogram -> per-block partial counts in ws --
__global__ __launch_bounds__(TPB) void count_kernel(const int* __restrict__ y,
                                                    int* __restrict__ part) {
    const int b = blockIdx.x >> 4, seg = blockIdx.x & 15;
    const int tid = threadIdx.x, lane = tid & 63, w = tid >> 6;
    const int4* yp = (const int4*)(y + (size_t)b * NPIX + seg * SEGPIX);
    int r[NCLS];
    #pragma unroll
    for (int k = 0; k < NCLS; ++k) r[k] = 0;
    #pragma unroll
    for (int j = 0; j < 4; ++j) {
        int4 l = yp[j * TPB + tid];
        #pragma unroll
        for (int k = 0; k < NCLS; ++k)
            r[k] += (l.x == k) + (l.y == k) + (l.z == k) + (l.w == k);
    }
    __shared__ int red[4][NCLS];
    #pragma unroll
    for (int k = 0; k < NCLS; ++k) {
        int v = r[k];
        for (int off = 32; off > 0; off >>= 1) v += __shfl_down(v, off);
        if (lane == 0) red[w][k] = v;
    }
    __syncthreads();
    if (tid < NCLS)
        part[blockIdx.x * NCLS + tid] =
            red[0][tid] + red[1][tid] + red[2][tid] + red[3][tid];
}

// ---- kernel 2: per-(batch, channel-pair) moments, packed-f32 accumulation --
__global__ __launch_bounds__(TPB) void moment_kernel(const float* __restrict__ x,
                                                     const int* __restrict__ y,
                                                     const int* __restrict__ part,
                                                     float* __restrict__ out) {
    const int tid = threadIdx.x, lane = tid & 63, w = tid >> 6;
    const int cp = blockIdx.x;          // channel pair: channels 2cp, 2cp+1
    const int b  = blockIdx.y;

    v2f s2[NCLS], q2[NCLS];             // {ch_a, ch_b} per class
    #pragma unroll
    for (int k = 0; k < NCLS; ++k) { s2[k] = (v2f)0.f; q2[k] = (v2f)0.f; }

    const float4* xa = (const float4*)(x + ((size_t)(b * NCH + 2 * cp)) * NPIX);
    const float4* xb = xa + NPIX / 4;
    const int4*   yp = (const int4*)(y + (size_t)b * NPIX);

    for (int it = tid; it < NPIX / 4; it += TPB) {   // 64 iterations
        float4 va = xa[it];
        float4 vb = xb[it];
        int4   l  = yp[it];
        #pragma unroll
        for (int k = 0; k < NCLS; ++k) {
            v2f t;
            bool m;
            m = (l.x == k); t.x = m ? va.x : 0.f; t.y = m ? vb.x : 0.f;
            asm("v_pk_add_f32 %0, %0, %1" : "+v"(s2[k]) : "v"(t));
            asm("v_pk_fma_f32 %0, %1, %1, %0" : "+v"(q2[k]) : "v"(t));
            m = (l.y == k); t.x = m ? va.y : 0.f; t.y = m ? vb.y : 0.f;
            asm("v_pk_add_f32 %0, %0, %1" : "+v"(s2[k]) : "v"(t));
            asm("v_pk_fma_f32 %0, %1, %1, %0" : "+v"(q2[k]) : "v"(t));
            m = (l.z == k); t.x = m ? va.z : 0.f; t.y = m ? vb.z : 0.f;
            asm("v_pk_add_f32 %0, %0, %1" : "+v"(s2[k]) : "v"(t));
            asm("v_pk_fma_f32 %0, %1, %1, %0" : "+v"(q2[k]) : "v"(t));
            m = (l.w == k); t.x = m ? va.w : 0.f; t.y = m ? vb.w : 0.f;
            asm("v_pk_add_f32 %0, %0, %1" : "+v"(s2[k]) : "v"(t));
            asm("v_pk_fma_f32 %0, %1, %1, %0" : "+v"(q2[k]) : "v"(t));
        }
    }

    // 64-lane butterfly per class, then cross-wave combine in LDS.
    __shared__ float red[4][NCLS][4];   // [wave][class][sa,sb,qa,qb]
    #pragma unroll
    for (int k = 0; k < NCLS; ++k) {
        float sa = s2[k].x, sb = s2[k].y, qa = q2[k].x, qb = q2[k].y;
        for (int off = 32; off > 0; off >>= 1) {
            sa += __shfl_down(sa, off);
            sb += __shfl_down(sb, off);
            qa += __shfl_down(qa, off);
            qb += __shfl_down(qb, off);
        }
        if (lane == 0) { red[w][k][0] = sa; red[w][k][1] = sb; red[w][k][2] = qa; red[w][k][3] = qb; }
    }
    __syncthreads();

    if (tid < NCLS) {
        const int k = tid;
        float sa = 0.f, sb = 0.f, qa = 0.f, qb = 0.f;
        #pragma unroll
        for (int i = 0; i < 4; ++i) {
            sa += red[i][k][0]; sb += red[i][k][1];
            qa += red[i][k][2]; qb += red[i][k][3];
        }
        int n = 0;
        #pragma unroll
        for (int i = 0; i < CSEG; ++i) n += part[(b * CSEG + i) * NCLS + k];
        const float nf = (float)n;
        const bool valid = n > CNT_THRESH;
        const float inv  = 1.0f / fmaxf(nf, 1.0f);
        const float dinv = 1.0f / fmaxf(nf - 1.0f, 1.0f);
        float mean_a = sa * inv, mean_b = sb * inv;
        float var_a = fmaxf((qa - nf * mean_a * mean_a) * dinv, 0.0f);
        float var_b = fmaxf((qb - nf * mean_b * mean_b) * dinv, 0.0f);
        const int oa = (b * NCLS + k) * NCH + 2 * cp;
        out[oa]     = valid ? mean_a : 0.0f;
        out[oa + 1] = valid ? mean_b : 0.0f;
        out[NBATCH * NCLS * NCH + oa]     = valid ? (sqrtf(var_a) + EPSV) : 0.0f;
        out[NBATCH * NCLS * NCH + oa + 1] = valid ? (sqrtf(var_b) + EPSV) : 0.0f;
        if (cp == 0)
            out[2 * NBATCH * NCLS * NCH + b * NCLS + k] = valid ? 1.0f : 0.0f;
    }
}

extern "C" void kernel_launch(void* const* d_in, const int* in_sizes, int n_in,
                              void* d_out, int out_size, void* d_ws, size_t ws_size,
                              hipStream_t stream) {
    const float* x = (const float*)d_in[0];
    const int*   y = (const int*)d_in[1];
    float* out = (float*)d_out;
    int* part = (int*)d_ws;   // 64 * 19 ints of partial counts

    count_kernel<<<NBATCH * CSEG, TPB, 0, stream>>>(y, part);

    dim3 grid(NCH / 2, NBATCH);
    moment_kernel<<<grid, TPB, 0, stream>>>(x, y, part, out);
}